// Round 5
// baseline (1521.090 us; speedup 1.0000x reference)
//
#include <hip/hip_runtime.h>

#define LAT 64
#define NXCD 8        // MI355X XCDs; blockIdx % 8 -> XCD (perf heuristic only)
#define ELLC 64       // ELL row capacity (deg ~ Poisson(32); overflow handled)
#define WN 8192       // col-window: 8192 nodes * 256B = 2MB, fits one XCD L2

// ---------- graph build: single-pass ELL, XCD-exclusive row ranges ----------
// One atomic per directed edge (6.4M total, was 12.8M across count+fill).
// Rows in [lo,hi) are written only by blocks on one XCD -> col lines assemble
// in that XCD's L2. User rows come only from eu[d], item rows only from ei[d],
// so each bucket-group scans just the relevant half of the edge list.
__global__ void fill_ell_xcd_k(const int* __restrict__ eu, const int* __restrict__ ei,
                               int* __restrict__ cnt, int* __restrict__ colE,
                               int2* __restrict__ ovf, int* __restrict__ ovf_cnt,
                               int E, int U, int N, int bucketN, int ovf_cap) {
    int xcd = blockIdx.x & (NXCD - 1);
    int lo = xcd * bucketN;
    int hi = min(N, lo + bucketN);
    int tid = (blockIdx.x >> 3) * blockDim.x + threadIdx.x;
    int stride = (gridDim.x >> 3) * blockDim.x;
    if (lo < U) {                       // user-side rows for this bucket
        int ulo = lo, uhi = min(hi, U);
        for (int d = tid; d < E; d += stride) {
            int r = eu[d];
            if (r < ulo || r >= uhi) continue;
            int c = ei[d] + U;
            int pos = atomicAdd(&cnt[r], 1);
            if (pos < ELLC) colE[r * ELLC + pos] = c;
            else { int o = atomicAdd(ovf_cnt, 1); if (o < ovf_cap) ovf[o] = make_int2(r, c); }
        }
    }
    if (hi > U) {                       // item-side rows for this bucket
        int ilo = max(lo, U), ihi = hi;
        for (int d = tid; d < E; d += stride) {
            int r = ei[d] + U;
            if (r < ilo || r >= ihi) continue;
            int c = eu[d];
            int pos = atomicAdd(&cnt[r], 1);
            if (pos < ELLC) colE[r * ELLC + pos] = c;
            else { int o = atomicAdd(ovf_cnt, 1); if (o < ovf_cap) ovf[o] = make_int2(r, c); }
        }
    }
}

__global__ void dinv_k(const int* __restrict__ cnt, float* __restrict__ dinv, int N) {
    int i = blockIdx.x * blockDim.x + threadIdx.x;
    if (i >= N) return;
    int d = cnt[i];
    dinv[i] = (d > 0) ? rsqrtf((float)d) : 0.0f;
}

// ---------- embedding init ----------

__global__ void init_y_k(const float* __restrict__ ue, const float* __restrict__ ie,
                         const float* __restrict__ dinv, float* __restrict__ y,
                         int N, int U) {
    int idx = blockIdx.x * blockDim.x + threadIdx.x;
    if (idx >= N * LAT) return;
    int node = idx >> 6;
    float e = (node < U) ? ue[idx] : ie[idx - U * LAT];
    y[idx] = dinv[node] * e;
}

__global__ void init_q_k(const float* __restrict__ ue, const float* __restrict__ ie,
                         const int* __restrict__ users, const int* __restrict__ items,
                         float* __restrict__ qacc, int B, int U) {
    int wave = blockIdx.x * (blockDim.x >> 6) + (threadIdx.x >> 6);
    int lane = threadIdx.x & 63;
    if (wave >= 2 * B) return;
    int node = (wave < B) ? users[wave] : (items[wave - B] + U);
    float e = (node < U) ? ue[node * LAT + lane] : ie[(node - U) * LAT + lane];
    qacc[wave * LAT + lane] = e;
}

// ---------- propagation: col-window sweep for L2 locality ----------
// One wave per node; 4 groups x 16 lanes x float4. The row's <=64 col indices
// are cached in registers (16 per lane), then 13 windows of 8192 nodes are
// swept; gathers execute only for cols inside the current 2MB window, so all
// concurrent gathers on an XCD hit the same L2-resident slice of y.
__global__ void __launch_bounds__(256)
prop_win_k(const int* __restrict__ cnt, const int* __restrict__ colE,
           const float* __restrict__ dinv, const float* __restrict__ yin,
           float* __restrict__ yout, int N) {
    int wave = blockIdx.x * (blockDim.x >> 6) + (threadIdx.x >> 6);
    int lane = threadIdx.x & 63;
    if (wave >= N) return;
    int g = lane >> 4;         // group 0..3: neighbor j = 4*it + g
    int t = lane & 15;         // float4 slot within the row
    int len = min(cnt[wave], ELLC);
    const int* cp = colE + wave * ELLC;
    const float4* y4 = (const float4*)yin;
    int lm0 = max(len - 1, 0);

    int cidx[16];
#pragma unroll
    for (int it = 0; it < 16; ++it) {
        int j = (it << 2) + g;
        int cc = cp[min(j, lm0)];           // clamped: always in-bounds
        cidx[it] = (j < len) ? cc : 0x7fffffff;  // sentinel: outside all windows
    }

    float4 acc[4];
#pragma unroll
    for (int q = 0; q < 4; ++q) acc[q] = make_float4(0.f, 0.f, 0.f, 0.f);

    int nw = (N + WN - 1) / WN;
    for (int w = 0; w < nw; ++w) {
        int wlo = w * WN, whi = wlo + WN;
#pragma unroll
        for (int it = 0; it < 16; ++it) {
            int c = cidx[it];
            if (c >= wlo && c < whi) {      // 16-lane-group-uniform branch
                float4 v = y4[(size_t)c * 16 + t];
                acc[it & 3].x += v.x; acc[it & 3].y += v.y;
                acc[it & 3].z += v.z; acc[it & 3].w += v.w;
            }
        }
    }
    float sx = (acc[0].x + acc[1].x) + (acc[2].x + acc[3].x);
    float sy = (acc[0].y + acc[1].y) + (acc[2].y + acc[3].y);
    float sz = (acc[0].z + acc[1].z) + (acc[2].z + acc[3].z);
    float sw = (acc[0].w + acc[1].w) + (acc[2].w + acc[3].w);
    // reduce across the 4 groups; full wave active here
    sx += __shfl_xor(sx, 16); sy += __shfl_xor(sy, 16);
    sz += __shfl_xor(sz, 16); sw += __shfl_xor(sw, 16);
    sx += __shfl_xor(sx, 32); sy += __shfl_xor(sy, 32);
    sz += __shfl_xor(sz, 32); sw += __shfl_xor(sw, 32);
    if (g == 0) {
        float di = dinv[wave];
        float f = di * di;
        float4 r;
        r.x = f * sx; r.y = f * sy; r.z = f * sz; r.w = f * sw;
        ((float4*)yout)[wave * 16 + t] = r;   // every row written (len==0 -> 0)
    }
}

// rare ELL-overflow fix-up: yout[r] += dinv[r]^2 * yin[c]  (expected ~0 entries)
__global__ void ovf_add_k(const int2* __restrict__ ovf, const int* __restrict__ ovf_cnt,
                          const float* __restrict__ dinv, const float* __restrict__ yin,
                          float* __restrict__ yout, int cap) {
    int n = min(*ovf_cnt, cap);
    int wave = blockIdx.x * (blockDim.x >> 6) + (threadIdx.x >> 6);
    int lane = threadIdx.x & 63;
    int nwv = gridDim.x * (blockDim.x >> 6);
    for (int o = wave; o < n; o += nwv) {
        int r = ovf[o].x, c = ovf[o].y;
        float f = dinv[r] * dinv[r];
        atomicAdd(&yout[r * LAT + lane], f * yin[c * LAT + lane]);
    }
}

// after each prop: qacc += x = y / dinv at queried nodes
__global__ void qgather_k(const float* __restrict__ y, const float* __restrict__ dinv,
                          const int* __restrict__ users, const int* __restrict__ items,
                          float* __restrict__ qacc, int B, int U) {
    int wave = blockIdx.x * (blockDim.x >> 6) + (threadIdx.x >> 6);
    int lane = threadIdx.x & 63;
    if (wave >= 2 * B) return;
    int node = (wave < B) ? users[wave] : (items[wave - B] + U);
    float di = dinv[node];
    float r = (di > 0.0f) ? (1.0f / di) : 0.0f;
    qacc[wave * LAT + lane] += y[node * LAT + lane] * r;
}

// gamma[b] = dot(qacc[b], qacc[b+B]) / 25
__global__ void gamma_k(const float* __restrict__ qacc, float* __restrict__ out, int B) {
    int wave = blockIdx.x * (blockDim.x >> 6) + (threadIdx.x >> 6);
    int lane = threadIdx.x & 63;
    if (wave >= B) return;
    float p = qacc[wave * LAT + lane] * qacc[(wave + B) * LAT + lane];
#pragma unroll
    for (int off = 32; off > 0; off >>= 1) p += __shfl_down(p, off);
    if (lane == 0) out[wave] = p * (1.0f / 25.0f);
}

extern "C" void kernel_launch(void* const* d_in, const int* in_sizes, int n_in,
                              void* d_out, int out_size, void* d_ws, size_t ws_size,
                              hipStream_t stream) {
    const float* ue = (const float*)d_in[0];
    const float* ie = (const float*)d_in[1];
    const int* edge = (const int*)d_in[2];
    const int* users = (const int*)d_in[3];
    const int* items = (const int*)d_in[4];

    const int U = in_sizes[0] / LAT;
    const int I = in_sizes[1] / LAT;
    const int N = U + I;
    const int E = in_sizes[2] / 2;
    const int B = in_sizes[3];
    const int* eu = edge;
    const int* ei = edge + E;

    char* ws = (char*)d_ws;
    size_t off = 0;
    auto alloc = [&](size_t bytes) -> void* {
        void* p = ws + off;
        off += (bytes + 255) & ~(size_t)255;
        return p;
    };
    int*   cnt     = (int*)alloc((size_t)4 * N);
    float* dinv    = (float*)alloc((size_t)4 * N);
    int*   colE    = (int*)alloc((size_t)4 * N * ELLC);    // 25.6 MB
    float* yA      = (float*)alloc((size_t)4 * N * LAT);
    float* yB      = (float*)alloc((size_t)4 * N * LAT);
    float* qacc    = (float*)alloc((size_t)4 * 2 * B * LAT);
    int*   ovfc    = (int*)alloc(256);
    // overflow list gets whatever workspace remains (expected usage: ~0)
    size_t remain = (ws_size > off + 256) ? (ws_size - off - 256) : 0;
    int ovf_cap = (int)min((size_t)262144, remain / sizeof(int2));
    int2*  ovf     = (int2*)alloc((size_t)ovf_cap * sizeof(int2));

    hipMemsetAsync(cnt, 0, (size_t)4 * N, stream);
    hipMemsetAsync(ovfc, 0, 4, stream);

    const int tb = 256;
    const int bucketN = (N + NXCD - 1) / NXCD;

    fill_ell_xcd_k<<<2048, tb, 0, stream>>>(eu, ei, cnt, colE, ovf, ovfc,
                                            E, U, N, bucketN, ovf_cap);
    dinv_k<<<(N + tb - 1) / tb, tb, 0, stream>>>(cnt, dinv, N);

    init_y_k<<<(N * LAT + tb - 1) / tb, tb, 0, stream>>>(ue, ie, dinv, yA, N, U);
    const int wpb = tb / 64;
    init_q_k<<<(2 * B + wpb - 1) / wpb, tb, 0, stream>>>(ue, ie, users, items, qacc, B, U);

    int pgrid = (N + wpb - 1) / wpb;
    int qgrid = (2 * B + wpb - 1) / wpb;

    float* yin = yA;
    float* yout = yB;
    for (int layer = 0; layer < 4; ++layer) {
        prop_win_k<<<pgrid, tb, 0, stream>>>(cnt, colE, dinv, yin, yout, N);
        ovf_add_k<<<64, tb, 0, stream>>>(ovf, ovfc, dinv, yin, yout, ovf_cap);
        qgather_k<<<qgrid, tb, 0, stream>>>(yout, dinv, users, items, qacc, B, U);
        float* tmp = yin; yin = yout; yout = tmp;
    }

    gamma_k<<<(B + wpb - 1) / wpb, tb, 0, stream>>>(qacc, (float*)d_out, B);
}

// Round 6
// 424.889 us; speedup vs baseline: 3.5800x; 3.5800x over previous
//
#include <hip/hip_runtime.h>
#include <hip/hip_fp16.h>

#define LAT 64
#define NXCD 8        // MI355X XCDs; blockIdx % 8 -> XCD (perf heuristic only)
#define ELLC 64       // ELL row capacity (deg ~ Poisson(32); overflow handled)

// ---------- graph build: single-pass ELL, XCD-exclusive row ranges ----------
__global__ void fill_ell_xcd_k(const int* __restrict__ eu, const int* __restrict__ ei,
                               int* __restrict__ cnt, int* __restrict__ colE,
                               int2* __restrict__ ovf, int* __restrict__ ovf_cnt,
                               int E, int U, int N, int bucketN, int ovf_cap) {
    int xcd = blockIdx.x & (NXCD - 1);
    int lo = xcd * bucketN;
    int hi = min(N, lo + bucketN);
    int tid = (blockIdx.x >> 3) * blockDim.x + threadIdx.x;
    int stride = (gridDim.x >> 3) * blockDim.x;
    if (lo < U) {                       // user-side rows for this bucket
        int ulo = lo, uhi = min(hi, U);
        for (int d = tid; d < E; d += stride) {
            int r = eu[d];
            if (r < ulo || r >= uhi) continue;
            int c = ei[d] + U;
            int pos = atomicAdd(&cnt[r], 1);
            if (pos < ELLC) colE[r * ELLC + pos] = c;
            else { int o = atomicAdd(ovf_cnt, 1); if (o < ovf_cap) ovf[o] = make_int2(r, c); }
        }
    }
    if (hi > U) {                       // item-side rows for this bucket
        int ilo = max(lo, U), ihi = hi;
        for (int d = tid; d < E; d += stride) {
            int r = ei[d] + U;
            if (r < ilo || r >= ihi) continue;
            int c = eu[d];
            int pos = atomicAdd(&cnt[r], 1);
            if (pos < ELLC) colE[r * ELLC + pos] = c;
            else { int o = atomicAdd(ovf_cnt, 1); if (o < ovf_cap) ovf[o] = make_int2(r, c); }
        }
    }
}

__global__ void dinv_k(const int* __restrict__ cnt, float* __restrict__ dinv, int N) {
    int i = blockIdx.x * blockDim.x + threadIdx.x;
    if (i >= N) return;
    int d = cnt[i];
    dinv[i] = (d > 0) ? rsqrtf((float)d) : 0.0f;
}

// ---------- embedding init ----------

// y0 = fp16(dinv * e0); two halves per thread (packed store)
__global__ void init_y_h_k(const float* __restrict__ ue, const float* __restrict__ ie,
                           const float* __restrict__ dinv, __half* __restrict__ y,
                           int N, int U) {
    int i = blockIdx.x * blockDim.x + threadIdx.x;
    if (i >= N * 32) return;
    int idx = i * 2;
    int node = idx >> 6;
    const float* src = (node < U) ? (ue + idx) : (ie + (idx - U * LAT));
    float di = dinv[node];
    ((__half2*)y)[i] = __floats2half2_rn(di * src[0], di * src[1]);
}

// query accumulator initialized with e0 (fp32, exact) at the 2B queried nodes
__global__ void init_q_k(const float* __restrict__ ue, const float* __restrict__ ie,
                         const int* __restrict__ users, const int* __restrict__ items,
                         float* __restrict__ qacc, int B, int U) {
    int wave = blockIdx.x * (blockDim.x >> 6) + (threadIdx.x >> 6);
    int lane = threadIdx.x & 63;
    if (wave >= 2 * B) return;
    int node = (wave < B) ? users[wave] : (items[wave - B] + U);
    float e = (node < U) ? ue[node * LAT + lane] : ie[(node - U) * LAT + lane];
    qacc[wave * LAT + lane] = e;
}

// ---------- propagation: direct gather, fp16 rows ----------
// One wave per node; 8 groups x 8 lanes x 16B. Row = 64 halves = 128B; one
// global_load_dwordx4 across the wave gathers 8 neighbor rows (1KB). Cols are
// loaded once coalesced (256B) and broadcast in-loop via shfl (bounds are
// wave-uniform; all lanes active at every shfl). Accumulate in fp32.
__global__ void __launch_bounds__(256)
prop_h_k(const int* __restrict__ cnt, const int* __restrict__ colE,
         const float* __restrict__ dinv, const __half* __restrict__ yin,
         __half* __restrict__ yout, int N) {
    int wave = blockIdx.x * (blockDim.x >> 6) + (threadIdx.x >> 6);
    int lane = threadIdx.x & 63;
    if (wave >= N) return;
    int g = lane >> 3;        // group 0..7: neighbor j = 8*it + g
    int t = lane & 7;         // 16B chunk: dims 8t..8t+7
    int len = min(cnt[wave], ELLC);
    const int* cp = colE + wave * ELLC;
    int lm0 = max(len - 1, 0);
    int call = cp[min(lane, lm0)];        // one coalesced 256B col load
    const uint4* y16 = (const uint4*)yin; // y16[c*8 + t] = 8 halves

    float acc[8];
#pragma unroll
    for (int d = 0; d < 8; ++d) acc[d] = 0.f;

    int nb = (len + 7) >> 3;              // wave-uniform trip count (0..8)
    int it = 0;
    for (; it + 4 <= nb; it += 4) {
        int j0 = (it << 3) + g;
        int c0 = __shfl(call, j0);            // all lanes active
        int c1 = __shfl(call, j0 + 8);
        int c2 = __shfl(call, j0 + 16);
        int c3 = __shfl(call, j0 + 24);
        uint4 v0 = y16[(size_t)c0 * 8 + t];
        uint4 v1 = y16[(size_t)c1 * 8 + t];
        uint4 v2 = y16[(size_t)c2 * 8 + t];
        uint4 v3 = y16[(size_t)c3 * 8 + t];
        // j0..j0+24 < 8*nb <= len+7; only predicate needed per sub-block
        const uint4* vs[4] = {&v0, &v1, &v2, &v3};
#pragma unroll
        for (int q = 0; q < 4; ++q) {
            if (j0 + (q << 3) < len) {
                const __half2* h = (const __half2*)vs[q];
#pragma unroll
                for (int d = 0; d < 4; ++d) {
                    float2 f = __half22float2(h[d]);
                    acc[2 * d] += f.x; acc[2 * d + 1] += f.y;
                }
            }
        }
    }
    for (; it < nb; ++it) {
        int j0 = (it << 3) + g;
        int c0 = __shfl(call, j0);
        uint4 v0 = y16[(size_t)c0 * 8 + t];
        if (j0 < len) {
            const __half2* h = (const __half2*)&v0;
#pragma unroll
            for (int d = 0; d < 4; ++d) {
                float2 f = __half22float2(h[d]);
                acc[2 * d] += f.x; acc[2 * d + 1] += f.y;
            }
        }
    }
    // reduce across the 8 groups (lanes t, t+8, ..., t+56); full wave active
#pragma unroll
    for (int d = 0; d < 8; ++d) {
        acc[d] += __shfl_xor(acc[d], 8);
        acc[d] += __shfl_xor(acc[d], 16);
        acc[d] += __shfl_xor(acc[d], 32);
    }
    if (g == 0) {
        float di = dinv[wave];
        float f = di * di;
        __half2 o[4];
#pragma unroll
        for (int d = 0; d < 4; ++d)
            o[d] = __floats2half2_rn(f * acc[2 * d], f * acc[2 * d + 1]);
        ((uint4*)yout)[(size_t)wave * 8 + t] = *(const uint4*)o;
    }
}

// rare ELL-overflow fix-up: yout[r] += dinv[r]^2 * yin[c], exact via CAS on
// packed half2 (expected ~0 entries; correctness does not depend on that)
__global__ void ovf_add_h_k(const int2* __restrict__ ovf, const int* __restrict__ ovf_cnt,
                            const float* __restrict__ dinv, const __half* __restrict__ yin,
                            __half* __restrict__ yout, int cap) {
    int n = min(*ovf_cnt, cap);
    int wave = blockIdx.x * (blockDim.x >> 6) + (threadIdx.x >> 6);
    int lane = threadIdx.x & 63;
    int nwv = gridDim.x * (blockDim.x >> 6);
    for (int o = wave; o < n; o += nwv) {
        int r = ovf[o].x, c = ovf[o].y;
        if (lane < 32) {
            float f = dinv[r] * dinv[r];
            __half2 v = ((const __half2*)(yin + (size_t)c * LAT))[lane];
            float ax = f * __low2float(v), ay = f * __high2float(v);
            unsigned int* addr = (unsigned int*)(yout + (size_t)r * LAT) + lane;
            unsigned int old = *addr;
            while (true) {
                __half2 oh = *(__half2*)&old;
                __half2 nh = __floats2half2_rn(__low2float(oh) + ax, __high2float(oh) + ay);
                unsigned int nu = *(unsigned int*)&nh;
                unsigned int prev = atomicCAS(addr, old, nu);
                if (prev == old) break;
                old = prev;
            }
        }
    }
}

// after each prop: qacc += x = y / dinv at queried nodes (fp32 accumulate)
__global__ void qgather_h_k(const __half* __restrict__ y, const float* __restrict__ dinv,
                            const int* __restrict__ users, const int* __restrict__ items,
                            float* __restrict__ qacc, int B, int U) {
    int wave = blockIdx.x * (blockDim.x >> 6) + (threadIdx.x >> 6);
    int lane = threadIdx.x & 63;
    if (wave >= 2 * B) return;
    int node = (wave < B) ? users[wave] : (items[wave - B] + U);
    float di = dinv[node];
    float r = (di > 0.0f) ? (1.0f / di) : 0.0f;
    qacc[wave * LAT + lane] += __half2float(y[(size_t)node * LAT + lane]) * r;
}

// gamma[b] = dot(qacc[b], qacc[b+B]) / 25
__global__ void gamma_k(const float* __restrict__ qacc, float* __restrict__ out, int B) {
    int wave = blockIdx.x * (blockDim.x >> 6) + (threadIdx.x >> 6);
    int lane = threadIdx.x & 63;
    if (wave >= B) return;
    float p = qacc[wave * LAT + lane] * qacc[(wave + B) * LAT + lane];
#pragma unroll
    for (int off = 32; off > 0; off >>= 1) p += __shfl_down(p, off);
    if (lane == 0) out[wave] = p * (1.0f / 25.0f);
}

extern "C" void kernel_launch(void* const* d_in, const int* in_sizes, int n_in,
                              void* d_out, int out_size, void* d_ws, size_t ws_size,
                              hipStream_t stream) {
    const float* ue = (const float*)d_in[0];
    const float* ie = (const float*)d_in[1];
    const int* edge = (const int*)d_in[2];
    const int* users = (const int*)d_in[3];
    const int* items = (const int*)d_in[4];

    const int U = in_sizes[0] / LAT;
    const int I = in_sizes[1] / LAT;
    const int N = U + I;
    const int E = in_sizes[2] / 2;
    const int B = in_sizes[3];
    const int* eu = edge;
    const int* ei = edge + E;

    char* ws = (char*)d_ws;
    size_t off = 0;
    auto alloc = [&](size_t bytes) -> void* {
        void* p = ws + off;
        off += (bytes + 255) & ~(size_t)255;
        return p;
    };
    int*    cnt  = (int*)alloc((size_t)4 * N);
    float*  dinv = (float*)alloc((size_t)4 * N);
    int*    colE = (int*)alloc((size_t)4 * N * ELLC);      // 25.6 MB
    __half* yA   = (__half*)alloc((size_t)2 * N * LAT);    // 12.8 MB
    __half* yB   = (__half*)alloc((size_t)2 * N * LAT);
    float*  qacc = (float*)alloc((size_t)4 * 2 * B * LAT);
    int*    ovfc = (int*)alloc(256);
    size_t remain = (ws_size > off + 256) ? (ws_size - off - 256) : 0;
    int ovf_cap = (int)min((size_t)262144, remain / sizeof(int2));
    int2*   ovf  = (int2*)alloc((size_t)ovf_cap * sizeof(int2));

    hipMemsetAsync(cnt, 0, (size_t)4 * N, stream);
    hipMemsetAsync(ovfc, 0, 4, stream);

    const int tb = 256;
    const int bucketN = (N + NXCD - 1) / NXCD;

    fill_ell_xcd_k<<<2048, tb, 0, stream>>>(eu, ei, cnt, colE, ovf, ovfc,
                                            E, U, N, bucketN, ovf_cap);
    dinv_k<<<(N + tb - 1) / tb, tb, 0, stream>>>(cnt, dinv, N);

    init_y_h_k<<<(N * 32 + tb - 1) / tb, tb, 0, stream>>>(ue, ie, dinv, yA, N, U);
    const int wpb = tb / 64;
    init_q_k<<<(2 * B + wpb - 1) / wpb, tb, 0, stream>>>(ue, ie, users, items, qacc, B, U);

    int pgrid = (N + wpb - 1) / wpb;
    int qgrid = (2 * B + wpb - 1) / wpb;

    __half* yin = yA;
    __half* yout = yB;
    for (int layer = 0; layer < 4; ++layer) {
        prop_h_k<<<pgrid, tb, 0, stream>>>(cnt, colE, dinv, yin, yout, N);
        ovf_add_h_k<<<64, tb, 0, stream>>>(ovf, ovfc, dinv, yin, yout, ovf_cap);
        qgather_h_k<<<qgrid, tb, 0, stream>>>(yout, dinv, users, items, qacc, B, U);
        __half* tmp = yin; yin = yout; yout = tmp;
    }

    gamma_k<<<(B + wpb - 1) / wpb, tb, 0, stream>>>(qacc, (float*)d_out, B);
}

// Round 7
// 356.567 us; speedup vs baseline: 4.2659x; 1.1916x over previous
//
#include <hip/hip_runtime.h>
#include <hip/hip_fp16.h>

#define LAT 64
#define ELLC 64       // ELL row capacity (deg ~ Poisson(32); overflow handled)
#define RB 256        // rows per bucket
#define RBSH 8
#define MAXBUK 512    // static LDS sizing; nbuk = ceil(N/256) = 391 for N=100k

// ---------- phase 1: bin directed edges by row-bucket ----------
// Global atomics: one reservation per (block,bucket) ~= 100k total (vs 3.2M
// per-edge). Packed word: (r & 255) << 17 | c   (needs N <= 131072).
__global__ void __launch_bounds__(256)
bin_k(const int* __restrict__ eu, const int* __restrict__ ei,
      int* __restrict__ gcur, unsigned int* __restrict__ bbuf,
      int2* __restrict__ ovf, int* __restrict__ ovfc,
      int E, int U, int nbuk, int cap, int ovf_cap) {
    __shared__ int lcnt[MAXBUK];
    __shared__ int lbase[MAXBUK];
    int E2 = 2 * E;
    for (int i = threadIdx.x; i < nbuk; i += blockDim.x) lcnt[i] = 0;
    __syncthreads();
    int chunk = (E2 + gridDim.x - 1) / gridDim.x;
    int d0 = blockIdx.x * chunk;
    int d1 = min(E2, d0 + chunk);
    for (int d = d0 + threadIdx.x; d < d1; d += blockDim.x) {
        int r = (d < E) ? eu[d] : (ei[d - E] + U);
        atomicAdd(&lcnt[r >> RBSH], 1);
    }
    __syncthreads();
    for (int b = threadIdx.x; b < nbuk; b += blockDim.x)
        lbase[b] = atomicAdd(&gcur[b], lcnt[b]);      // global reservation
    __syncthreads();
    for (int d = d0 + threadIdx.x; d < d1; d += blockDim.x) {
        int r, c;
        if (d < E) { r = eu[d]; c = ei[d] + U; }
        else       { r = ei[d - E] + U; c = eu[d - E]; }
        int b = r >> RBSH;
        int pos = atomicAdd(&lbase[b], 1);            // LDS atomic (fast)
        if (pos < cap)
            bbuf[(size_t)b * cap + pos] = ((unsigned)(r & (RB - 1)) << 17) | (unsigned)c;
        else { int o = atomicAdd(ovfc, 1); if (o < ovf_cap) ovf[o] = make_int2(r, c); }
    }
}

// ---------- phase 2: per-bucket ELL build, LDS counters (0 global atomics) ----
__global__ void __launch_bounds__(256)
build_k(const unsigned int* __restrict__ bbuf, const int* __restrict__ gcur,
        int* __restrict__ cnt, int* __restrict__ colE,
        int2* __restrict__ rovf, int* __restrict__ rovfc,
        int N, int cap, int rovf_cap) {
    __shared__ int lcnt[RB];
    int b = blockIdx.x;
    for (int i = threadIdx.x; i < RB; i += blockDim.x) lcnt[i] = 0;
    __syncthreads();
    int nb = min(gcur[b], cap);
    const unsigned int* src = bbuf + (size_t)b * cap;
    for (int e = threadIdx.x; e < nb; e += blockDim.x) {
        unsigned w = src[e];
        int r7 = (int)(w >> 17);
        int c = (int)(w & 0x1FFFF);
        int pos = atomicAdd(&lcnt[r7], 1);
        int r = (b << RBSH) + r7;
        if (pos < ELLC) colE[(size_t)r * ELLC + pos] = c;   // 32KB L2 window
        else { int o = atomicAdd(rovfc, 1); if (o < rovf_cap) rovf[o] = make_int2(r, c); }
    }
    __syncthreads();
    for (int i = threadIdx.x; i < RB; i += blockDim.x) {
        int r = (b << RBSH) + i;
        if (r < N) cnt[r] = lcnt[i];
    }
}

// bin-phase spill fix-up (expected 0 entries; exact)
__global__ void spill_fix_k(const int2* __restrict__ ovf, const int* __restrict__ ovfc,
                            int* __restrict__ cnt, int* __restrict__ colE,
                            int2* __restrict__ rovf, int* __restrict__ rovfc,
                            int ovf_cap, int rovf_cap) {
    int n = min(*ovfc, ovf_cap);
    int stride = gridDim.x * blockDim.x;
    for (int i = blockIdx.x * blockDim.x + threadIdx.x; i < n; i += stride) {
        int r = ovf[i].x, c = ovf[i].y;
        int pos = atomicAdd(&cnt[r], 1);
        if (pos < ELLC) colE[(size_t)r * ELLC + pos] = c;
        else { int o = atomicAdd(rovfc, 1); if (o < rovf_cap) rovf[o] = make_int2(r, c); }
    }
}

__global__ void dinv_k(const int* __restrict__ cnt, float* __restrict__ dinv, int N) {
    int i = blockIdx.x * blockDim.x + threadIdx.x;
    if (i >= N) return;
    int d = cnt[i];
    dinv[i] = (d > 0) ? rsqrtf((float)d) : 0.0f;
}

// ---------- embedding init ----------

__global__ void init_y_h_k(const float* __restrict__ ue, const float* __restrict__ ie,
                           const float* __restrict__ dinv, __half* __restrict__ y,
                           int N, int U) {
    int i = blockIdx.x * blockDim.x + threadIdx.x;
    if (i >= N * 32) return;
    int idx = i * 2;
    int node = idx >> 6;
    const float* src = (node < U) ? (ue + idx) : (ie + (idx - U * LAT));
    float di = dinv[node];
    ((__half2*)y)[i] = __floats2half2_rn(di * src[0], di * src[1]);
}

__global__ void init_q_k(const float* __restrict__ ue, const float* __restrict__ ie,
                         const int* __restrict__ users, const int* __restrict__ items,
                         float* __restrict__ qacc, int B, int U) {
    int wave = blockIdx.x * (blockDim.x >> 6) + (threadIdx.x >> 6);
    int lane = threadIdx.x & 63;
    if (wave >= 2 * B) return;
    int node = (wave < B) ? users[wave] : (items[wave - B] + U);
    float e = (node < U) ? ue[node * LAT + lane] : ie[(node - U) * LAT + lane];
    qacc[wave * LAT + lane] = e;
}

// ---------- propagation: direct gather, fp16 rows (proven R6) ----------
__global__ void __launch_bounds__(256)
prop_h_k(const int* __restrict__ cnt, const int* __restrict__ colE,
         const float* __restrict__ dinv, const __half* __restrict__ yin,
         __half* __restrict__ yout, int N) {
    int wave = blockIdx.x * (blockDim.x >> 6) + (threadIdx.x >> 6);
    int lane = threadIdx.x & 63;
    if (wave >= N) return;
    int g = lane >> 3;        // group 0..7: neighbor j = 8*it + g
    int t = lane & 7;         // 16B chunk: dims 8t..8t+7
    int len = min(cnt[wave], ELLC);
    const int* cp = colE + (size_t)wave * ELLC;
    int lm0 = max(len - 1, 0);
    int call = cp[min(lane, lm0)];        // one coalesced 256B col load
    const uint4* y16 = (const uint4*)yin;

    float acc[8];
#pragma unroll
    for (int d = 0; d < 8; ++d) acc[d] = 0.f;

    int nb = (len + 7) >> 3;              // wave-uniform trip count (0..8)
    int it = 0;
    for (; it + 4 <= nb; it += 4) {
        int j0 = (it << 3) + g;
        int c0 = __shfl(call, j0);
        int c1 = __shfl(call, j0 + 8);
        int c2 = __shfl(call, j0 + 16);
        int c3 = __shfl(call, j0 + 24);
        uint4 v0 = y16[(size_t)c0 * 8 + t];
        uint4 v1 = y16[(size_t)c1 * 8 + t];
        uint4 v2 = y16[(size_t)c2 * 8 + t];
        uint4 v3 = y16[(size_t)c3 * 8 + t];
        const uint4* vs[4] = {&v0, &v1, &v2, &v3};
#pragma unroll
        for (int q = 0; q < 4; ++q) {
            if (j0 + (q << 3) < len) {
                const __half2* h = (const __half2*)vs[q];
#pragma unroll
                for (int d = 0; d < 4; ++d) {
                    float2 f = __half22float2(h[d]);
                    acc[2 * d] += f.x; acc[2 * d + 1] += f.y;
                }
            }
        }
    }
    for (; it < nb; ++it) {
        int j0 = (it << 3) + g;
        int c0 = __shfl(call, j0);
        uint4 v0 = y16[(size_t)c0 * 8 + t];
        if (j0 < len) {
            const __half2* h = (const __half2*)&v0;
#pragma unroll
            for (int d = 0; d < 4; ++d) {
                float2 f = __half22float2(h[d]);
                acc[2 * d] += f.x; acc[2 * d + 1] += f.y;
            }
        }
    }
#pragma unroll
    for (int d = 0; d < 8; ++d) {
        acc[d] += __shfl_xor(acc[d], 8);
        acc[d] += __shfl_xor(acc[d], 16);
        acc[d] += __shfl_xor(acc[d], 32);
    }
    if (g == 0) {
        float di = dinv[wave];
        float f = di * di;
        __half2 o[4];
#pragma unroll
        for (int d = 0; d < 4; ++d)
            o[d] = __floats2half2_rn(f * acc[2 * d], f * acc[2 * d + 1]);
        ((uint4*)yout)[(size_t)wave * 8 + t] = *(const uint4*)o;
    }
}

// rare ELL row-overflow fix-up (exact via CAS on packed half2)
__global__ void ovf_add_h_k(const int2* __restrict__ rovf, const int* __restrict__ rovfc,
                            const float* __restrict__ dinv, const __half* __restrict__ yin,
                            __half* __restrict__ yout, int cap) {
    int n = min(*rovfc, cap);
    int wave = blockIdx.x * (blockDim.x >> 6) + (threadIdx.x >> 6);
    int lane = threadIdx.x & 63;
    int nwv = gridDim.x * (blockDim.x >> 6);
    for (int o = wave; o < n; o += nwv) {
        int r = rovf[o].x, c = rovf[o].y;
        if (lane < 32) {
            float f = dinv[r] * dinv[r];
            __half2 v = ((const __half2*)(yin + (size_t)c * LAT))[lane];
            float ax = f * __low2float(v), ay = f * __high2float(v);
            unsigned int* addr = (unsigned int*)(yout + (size_t)r * LAT) + lane;
            unsigned int old = *addr;
            while (true) {
                __half2 oh = *(__half2*)&old;
                __half2 nh = __floats2half2_rn(__low2float(oh) + ax, __high2float(oh) + ay);
                unsigned int nu = *(unsigned int*)&nh;
                unsigned int prev = atomicCAS(addr, old, nu);
                if (prev == old) break;
                old = prev;
            }
        }
    }
}

__global__ void qgather_h_k(const __half* __restrict__ y, const float* __restrict__ dinv,
                            const int* __restrict__ users, const int* __restrict__ items,
                            float* __restrict__ qacc, int B, int U) {
    int wave = blockIdx.x * (blockDim.x >> 6) + (threadIdx.x >> 6);
    int lane = threadIdx.x & 63;
    if (wave >= 2 * B) return;
    int node = (wave < B) ? users[wave] : (items[wave - B] + U);
    float di = dinv[node];
    float r = (di > 0.0f) ? (1.0f / di) : 0.0f;
    qacc[wave * LAT + lane] += __half2float(y[(size_t)node * LAT + lane]) * r;
}

__global__ void gamma_k(const float* __restrict__ qacc, float* __restrict__ out, int B) {
    int wave = blockIdx.x * (blockDim.x >> 6) + (threadIdx.x >> 6);
    int lane = threadIdx.x & 63;
    if (wave >= B) return;
    float p = qacc[wave * LAT + lane] * qacc[(wave + B) * LAT + lane];
#pragma unroll
    for (int off = 32; off > 0; off >>= 1) p += __shfl_down(p, off);
    if (lane == 0) out[wave] = p * (1.0f / 25.0f);
}

extern "C" void kernel_launch(void* const* d_in, const int* in_sizes, int n_in,
                              void* d_out, int out_size, void* d_ws, size_t ws_size,
                              hipStream_t stream) {
    const float* ue = (const float*)d_in[0];
    const float* ie = (const float*)d_in[1];
    const int* edge = (const int*)d_in[2];
    const int* users = (const int*)d_in[3];
    const int* items = (const int*)d_in[4];

    const int U = in_sizes[0] / LAT;
    const int I = in_sizes[1] / LAT;
    const int N = U + I;
    const int E = in_sizes[2] / 2;
    const int B = in_sizes[3];
    const int* eu = edge;
    const int* ei = edge + E;

    const int nbuk = (N + RB - 1) / RB;                   // 391 for N=100k
    const int cap = ((2 * E / nbuk) * 5 / 4 + 255) & ~255; // ~25% slack

    char* ws = (char*)d_ws;
    size_t off = 0;
    auto alloc = [&](size_t bytes) -> void* {
        void* p = ws + off;
        off += (bytes + 255) & ~(size_t)255;
        return p;
    };
    int*      cnt  = (int*)alloc((size_t)4 * N);
    float*    dinv = (float*)alloc((size_t)4 * N);
    int*      colE = (int*)alloc((size_t)4 * N * ELLC);     // 25.6 MB
    __half*   yA   = (__half*)alloc((size_t)2 * N * LAT);   // 12.8 MB
    __half*   yB   = (__half*)alloc((size_t)2 * N * LAT);
    float*    qacc = (float*)alloc((size_t)4 * 2 * B * LAT);
    unsigned* bbuf = (unsigned*)alloc((size_t)4 * nbuk * cap);  // ~16 MB
    int*      gcur = (int*)alloc((size_t)4 * nbuk);
    int*      ovfc = (int*)alloc(256);   // [0]=bin spill, [1]=row ovf
    size_t remain = (ws_size > off + 256) ? (ws_size - off - 256) : 0;
    int ovf_cap = (int)min((size_t)131072, remain / (2 * sizeof(int2)));
    int2* ovf  = (int2*)alloc((size_t)ovf_cap * sizeof(int2));
    int2* rovf = (int2*)alloc((size_t)ovf_cap * sizeof(int2));
    int* rovfc = ovfc + 64;

    hipMemsetAsync(gcur, 0, (size_t)4 * nbuk, stream);
    hipMemsetAsync(ovfc, 0, 256, stream);

    const int tb = 256;

    bin_k<<<256, tb, 0, stream>>>(eu, ei, gcur, bbuf, ovf, ovfc, E, U, nbuk, cap, ovf_cap);
    build_k<<<nbuk, tb, 0, stream>>>(bbuf, gcur, cnt, colE, rovf, rovfc, N, cap, ovf_cap);
    spill_fix_k<<<16, tb, 0, stream>>>(ovf, ovfc, cnt, colE, rovf, rovfc, ovf_cap, ovf_cap);
    dinv_k<<<(N + tb - 1) / tb, tb, 0, stream>>>(cnt, dinv, N);

    init_y_h_k<<<(N * 32 + tb - 1) / tb, tb, 0, stream>>>(ue, ie, dinv, yA, N, U);
    const int wpb = tb / 64;
    init_q_k<<<(2 * B + wpb - 1) / wpb, tb, 0, stream>>>(ue, ie, users, items, qacc, B, U);

    int pgrid = (N + wpb - 1) / wpb;
    int qgrid = (2 * B + wpb - 1) / wpb;

    __half* yin = yA;
    __half* yout = yB;
    for (int layer = 0; layer < 4; ++layer) {
        prop_h_k<<<pgrid, tb, 0, stream>>>(cnt, colE, dinv, yin, yout, N);
        ovf_add_h_k<<<64, tb, 0, stream>>>(rovf, rovfc, dinv, yin, yout, ovf_cap);
        qgather_h_k<<<qgrid, tb, 0, stream>>>(yout, dinv, users, items, qacc, B, U);
        __half* tmp = yin; yin = yout; yout = tmp;
    }

    gamma_k<<<(B + wpb - 1) / wpb, tb, 0, stream>>>(qacc, (float*)d_out, B);
}

// Round 9
// 335.457 us; speedup vs baseline: 4.5344x; 1.0629x over previous
//
#include <hip/hip_runtime.h>
#include <hip/hip_fp16.h>

#define LAT 64
#define ELLC 64       // ELL row capacity (deg ~ Poisson(32); overflow handled)
#define RB 256        // rows per bucket
#define RBSH 8
#define MAXBUK 512    // static LDS sizing; nbuk = ceil(N/256) = 391 for N=100k

// ---------- phase 1: bin directed edges by row-bucket ----------
// Global atomics: one reservation per (block,bucket) ~= 100k total. 1024
// threads/block for latency hiding (R7: 256 thr -> 9.5% occupancy, 0.5 TB/s).
// Packed word: (r & 255) << 17 | c   (needs N <= 131072).
__global__ void __launch_bounds__(1024)
bin_k(const int* __restrict__ eu, const int* __restrict__ ei,
      int* __restrict__ gcur, unsigned int* __restrict__ bbuf,
      int2* __restrict__ ovf, int* __restrict__ ovfc,
      int E, int U, int nbuk, int cap, int ovf_cap) {
    __shared__ int lcnt[MAXBUK];
    __shared__ int lbase[MAXBUK];
    int E2 = 2 * E;
    for (int i = threadIdx.x; i < nbuk; i += blockDim.x) lcnt[i] = 0;
    __syncthreads();
    int chunk = (E2 + gridDim.x - 1) / gridDim.x;
    int d0 = blockIdx.x * chunk;
    int d1 = min(E2, d0 + chunk);
    for (int d = d0 + threadIdx.x; d < d1; d += blockDim.x) {
        int r = (d < E) ? eu[d] : (ei[d - E] + U);
        atomicAdd(&lcnt[r >> RBSH], 1);
    }
    __syncthreads();
    for (int b = threadIdx.x; b < nbuk; b += blockDim.x)
        lbase[b] = atomicAdd(&gcur[b], lcnt[b]);      // global reservation
    __syncthreads();
    for (int d = d0 + threadIdx.x; d < d1; d += blockDim.x) {
        int r, c;
        if (d < E) { r = eu[d]; c = ei[d] + U; }
        else       { r = ei[d - E] + U; c = eu[d - E]; }
        int b = r >> RBSH;
        int pos = atomicAdd(&lbase[b], 1);            // LDS atomic (fast)
        if (pos < cap)
            bbuf[(size_t)b * cap + pos] = ((unsigned)(r & (RB - 1)) << 17) | (unsigned)c;
        else { int o = atomicAdd(ovfc, 1); if (o < ovf_cap) ovf[o] = make_int2(r, c); }
    }
}

// ---------- phase 2: per-bucket ELL build + dinv, LDS counters ----------
__global__ void __launch_bounds__(1024)
build_k(const unsigned int* __restrict__ bbuf, const int* __restrict__ gcur,
        int* __restrict__ cnt, int* __restrict__ colE, float* __restrict__ dinv,
        int2* __restrict__ rovf, int* __restrict__ rovfc,
        int N, int cap, int rovf_cap) {
    __shared__ int lcnt[RB];
    int b = blockIdx.x;
    for (int i = threadIdx.x; i < RB; i += blockDim.x) lcnt[i] = 0;
    __syncthreads();
    int nb = min(gcur[b], cap);
    const unsigned int* src = bbuf + (size_t)b * cap;
    for (int e = threadIdx.x; e < nb; e += blockDim.x) {
        unsigned w = src[e];
        int r7 = (int)(w >> 17);
        int c = (int)(w & 0x1FFFF);
        int pos = atomicAdd(&lcnt[r7], 1);
        int r = (b << RBSH) + r7;
        if (pos < ELLC) colE[(size_t)r * ELLC + pos] = c;   // 64KB L2 window
        else { int o = atomicAdd(rovfc, 1); if (o < rovf_cap) rovf[o] = make_int2(r, c); }
    }
    __syncthreads();
    for (int i = threadIdx.x; i < RB; i += blockDim.x) {
        int r = (b << RBSH) + i;
        if (r < N) {
            int d = lcnt[i];
            cnt[r] = d;
            dinv[r] = (d > 0) ? rsqrtf((float)d) : 0.0f;  // spill rows fixed later
        }
    }
}

// bin-phase spill fix-up (expected 0 entries; exact)
__global__ void spill_fix_k(const int2* __restrict__ ovf, const int* __restrict__ ovfc,
                            int* __restrict__ cnt, int* __restrict__ colE,
                            int2* __restrict__ rovf, int* __restrict__ rovfc,
                            int ovf_cap, int rovf_cap) {
    int n = min(*ovfc, ovf_cap);
    int stride = gridDim.x * blockDim.x;
    for (int i = blockIdx.x * blockDim.x + threadIdx.x; i < n; i += stride) {
        int r = ovf[i].x, c = ovf[i].y;
        int pos = atomicAdd(&cnt[r], 1);
        if (pos < ELLC) colE[(size_t)r * ELLC + pos] = c;
        else { int o = atomicAdd(rovfc, 1); if (o < rovf_cap) rovf[o] = make_int2(r, c); }
    }
}

// recompute dinv for spill-affected rows (runs after spill_fix; final cnt known)
__global__ void dinv_fix_k(const int2* __restrict__ ovf, const int* __restrict__ ovfc,
                           const int* __restrict__ cnt, float* __restrict__ dinv,
                           int ovf_cap) {
    int n = min(*ovfc, ovf_cap);
    int stride = gridDim.x * blockDim.x;
    for (int i = blockIdx.x * blockDim.x + threadIdx.x; i < n; i += stride) {
        int r = ovf[i].x;
        int d = cnt[r];
        dinv[r] = (d > 0) ? rsqrtf((float)d) : 0.0f;
    }
}

// ---------- embedding init ----------

__global__ void init_y_h_k(const float* __restrict__ ue, const float* __restrict__ ie,
                           const float* __restrict__ dinv, __half* __restrict__ y,
                           int N, int U) {
    int i = blockIdx.x * blockDim.x + threadIdx.x;
    if (i >= N * 32) return;
    int idx = i * 2;
    int node = idx >> 6;
    const float* src = (node < U) ? (ue + idx) : (ie + (idx - U * LAT));
    float di = dinv[node];
    ((__half2*)y)[i] = __floats2half2_rn(di * src[0], di * src[1]);
}

// ---------- propagation: direct gather, fp16 rows (R6-proven) ----------
// One wave per node; 8 groups x 8 lanes x 16B. Row = 64 halves = 128B; one
// global_load_dwordx4 across the wave gathers 8 neighbor rows (1KB). Cols
// loaded once coalesced (256B), broadcast via shfl (wave-uniform bounds; all
// lanes active at every shfl). Accumulate in fp32.
__global__ void __launch_bounds__(256)
prop_h_k(const int* __restrict__ cnt, const int* __restrict__ colE,
         const float* __restrict__ dinv, const __half* __restrict__ yin,
         __half* __restrict__ yout, int N) {
    int wave = blockIdx.x * (blockDim.x >> 6) + (threadIdx.x >> 6);
    int lane = threadIdx.x & 63;
    if (wave >= N) return;
    int g = lane >> 3;        // group 0..7: neighbor j = 8*it + g
    int t = lane & 7;         // 16B chunk: dims 8t..8t+7
    int len = min(cnt[wave], ELLC);
    const int* cp = colE + (size_t)wave * ELLC;
    int lm0 = max(len - 1, 0);
    int call = cp[min(lane, lm0)];        // one coalesced 256B col load
    const uint4* y16 = (const uint4*)yin;

    float2 acc[4];
#pragma unroll
    for (int d = 0; d < 4; ++d) acc[d] = make_float2(0.f, 0.f);

    int nb = (len + 7) >> 3;              // wave-uniform trip count (0..8)
    int it = 0;
    for (; it + 4 <= nb; it += 4) {
        int j0 = (it << 3) + g;
        int c0 = __shfl(call, j0);
        int c1 = __shfl(call, j0 + 8);
        int c2 = __shfl(call, j0 + 16);
        int c3 = __shfl(call, j0 + 24);
        uint4 v0 = y16[(size_t)c0 * 8 + t];
        uint4 v1 = y16[(size_t)c1 * 8 + t];
        uint4 v2 = y16[(size_t)c2 * 8 + t];
        uint4 v3 = y16[(size_t)c3 * 8 + t];
        if (j0 < len) {
            const __half2* h = (const __half2*)&v0;
#pragma unroll
            for (int d = 0; d < 4; ++d) { float2 f = __half22float2(h[d]); acc[d].x += f.x; acc[d].y += f.y; }
        }
        if (j0 + 8 < len) {
            const __half2* h = (const __half2*)&v1;
#pragma unroll
            for (int d = 0; d < 4; ++d) { float2 f = __half22float2(h[d]); acc[d].x += f.x; acc[d].y += f.y; }
        }
        if (j0 + 16 < len) {
            const __half2* h = (const __half2*)&v2;
#pragma unroll
            for (int d = 0; d < 4; ++d) { float2 f = __half22float2(h[d]); acc[d].x += f.x; acc[d].y += f.y; }
        }
        if (j0 + 24 < len) {
            const __half2* h = (const __half2*)&v3;
#pragma unroll
            for (int d = 0; d < 4; ++d) { float2 f = __half22float2(h[d]); acc[d].x += f.x; acc[d].y += f.y; }
        }
    }
    for (; it < nb; ++it) {
        int j0 = (it << 3) + g;
        int c0 = __shfl(call, j0);
        uint4 v0 = y16[(size_t)c0 * 8 + t];
        if (j0 < len) {
            const __half2* h = (const __half2*)&v0;
#pragma unroll
            for (int d = 0; d < 4; ++d) { float2 f = __half22float2(h[d]); acc[d].x += f.x; acc[d].y += f.y; }
        }
    }
#pragma unroll
    for (int d = 0; d < 4; ++d) {
        acc[d].x += __shfl_xor(acc[d].x, 8);  acc[d].y += __shfl_xor(acc[d].y, 8);
        acc[d].x += __shfl_xor(acc[d].x, 16); acc[d].y += __shfl_xor(acc[d].y, 16);
        acc[d].x += __shfl_xor(acc[d].x, 32); acc[d].y += __shfl_xor(acc[d].y, 32);
    }
    if (g == 0) {
        float di = dinv[wave];
        float f = di * di;
        __half2 o[4];
#pragma unroll
        for (int d = 0; d < 4; ++d)
            o[d] = __floats2half2_rn(f * acc[d].x, f * acc[d].y);
        ((uint4*)yout)[(size_t)wave * 8 + t] = *(const uint4*)o;
    }
}

// per-layer query gather: qacc (+)= x = yin/dinv at queried nodes
__global__ void qgather_h_k(const __half* __restrict__ y, const float* __restrict__ dinv,
                            const int* __restrict__ users, const int* __restrict__ items,
                            float* __restrict__ qacc, int B, int U, int first) {
    int wave = blockIdx.x * (blockDim.x >> 6) + (threadIdx.x >> 6);
    int lane = threadIdx.x & 63;
    if (wave >= 2 * B) return;
    int node = (wave < B) ? users[wave] : (items[wave - B] + U);
    float di = dinv[node];
    float r = (di > 0.0f) ? (1.0f / di) : 0.0f;
    float v = __half2float(y[(size_t)node * LAT + lane]) * r;
    if (first) qacc[wave * LAT + lane] = v;
    else       qacc[wave * LAT + lane] += v;
}

// rare ELL row-overflow fix-up (exact via CAS on packed half2)
__global__ void ovf_add_h_k(const int2* __restrict__ rovf, const int* __restrict__ rovfc,
                            const float* __restrict__ dinv, const __half* __restrict__ yin,
                            __half* __restrict__ yout, int cap) {
    int n = min(*rovfc, cap);
    int wave = blockIdx.x * (blockDim.x >> 6) + (threadIdx.x >> 6);
    int lane = threadIdx.x & 63;
    int nwv = gridDim.x * (blockDim.x >> 6);
    for (int o = wave; o < n; o += nwv) {
        int r = rovf[o].x, c = rovf[o].y;
        if (lane < 32) {
            float f = dinv[r] * dinv[r];
            __half2 v = ((const __half2*)(yin + (size_t)c * LAT))[lane];
            float ax = f * __low2float(v), ay = f * __high2float(v);
            unsigned int* addr = (unsigned int*)(yout + (size_t)r * LAT) + lane;
            unsigned int old = *addr;
            while (true) {
                __half2 oh = *(__half2*)&old;
                __half2 nh = __floats2half2_rn(__low2float(oh) + ax, __high2float(oh) + ay);
                unsigned int nu = *(unsigned int*)&nh;
                unsigned int prev = atomicCAS(addr, old, nu);
                if (prev == old) break;
                old = prev;
            }
        }
    }
}

// final: qacc += x4 at queried nodes, then gamma = dot/25 (fused last qgather)
__global__ void final_k(const float* __restrict__ qacc, const __half* __restrict__ y4,
                        const float* __restrict__ dinv,
                        const int* __restrict__ users, const int* __restrict__ items,
                        float* __restrict__ out, int B, int U) {
    int wave = blockIdx.x * (blockDim.x >> 6) + (threadIdx.x >> 6);
    int lane = threadIdx.x & 63;
    if (wave >= B) return;
    int un = users[wave];
    int in = items[wave] + U;
    float du = dinv[un], di = dinv[in];
    float ru = (du > 0.f) ? (1.f / du) : 0.f;
    float ri = (di > 0.f) ? (1.f / di) : 0.f;
    float au = qacc[wave * LAT + lane] + __half2float(y4[(size_t)un * LAT + lane]) * ru;
    float ai = qacc[(wave + B) * LAT + lane] + __half2float(y4[(size_t)in * LAT + lane]) * ri;
    float p = au * ai;
#pragma unroll
    for (int off = 32; off > 0; off >>= 1) p += __shfl_down(p, off);
    if (lane == 0) out[wave] = p * (1.0f / 25.0f);
}

extern "C" void kernel_launch(void* const* d_in, const int* in_sizes, int n_in,
                              void* d_out, int out_size, void* d_ws, size_t ws_size,
                              hipStream_t stream) {
    const float* ue = (const float*)d_in[0];
    const float* ie = (const float*)d_in[1];
    const int* edge = (const int*)d_in[2];
    const int* users = (const int*)d_in[3];
    const int* items = (const int*)d_in[4];

    const int U = in_sizes[0] / LAT;
    const int I = in_sizes[1] / LAT;
    const int N = U + I;
    const int E = in_sizes[2] / 2;
    const int B = in_sizes[3];
    const int* eu = edge;
    const int* ei = edge + E;

    const int nbuk = (N + RB - 1) / RB;                    // 391 for N=100k
    const int cap = ((2 * E / nbuk) * 5 / 4 + 255) & ~255; // ~25% slack

    char* ws = (char*)d_ws;
    size_t off = 0;
    auto alloc = [&](size_t bytes) -> void* {
        void* p = ws + off;
        off += (bytes + 255) & ~(size_t)255;
        return p;
    };
    int*      cnt  = (int*)alloc((size_t)4 * N);
    float*    dinv = (float*)alloc((size_t)4 * N);
    int*      colE = (int*)alloc((size_t)4 * N * ELLC);     // 25.6 MB
    __half*   yA   = (__half*)alloc((size_t)2 * N * LAT);   // 12.8 MB
    __half*   yB   = (__half*)alloc((size_t)2 * N * LAT);
    float*    qacc = (float*)alloc((size_t)4 * 2 * B * LAT);
    unsigned* bbuf = (unsigned*)alloc((size_t)4 * nbuk * cap);  // ~16 MB
    int*      gcur = (int*)alloc((size_t)4 * nbuk);
    int*      ovfc = (int*)alloc(256);   // [0]=bin spill, [64]=row ovf
    size_t remain = (ws_size > off + 256) ? (ws_size - off - 256) : 0;
    int ovf_cap = (int)min((size_t)131072, remain / (2 * sizeof(int2)));
    int2* ovf  = (int2*)alloc((size_t)ovf_cap * sizeof(int2));
    int2* rovf = (int2*)alloc((size_t)ovf_cap * sizeof(int2));
    int* rovfc = ovfc + 64;

    hipError_t _e;
    _e = hipMemsetAsync(gcur, 0, (size_t)4 * nbuk, stream); (void)_e;
    _e = hipMemsetAsync(ovfc, 0, 256, stream); (void)_e;

    const int tb = 256;

    bin_k<<<256, 1024, 0, stream>>>(eu, ei, gcur, bbuf, ovf, ovfc, E, U, nbuk, cap, ovf_cap);
    build_k<<<nbuk, 1024, 0, stream>>>(bbuf, gcur, cnt, colE, dinv, rovf, rovfc, N, cap, ovf_cap);
    spill_fix_k<<<16, tb, 0, stream>>>(ovf, ovfc, cnt, colE, rovf, rovfc, ovf_cap, ovf_cap);
    dinv_fix_k<<<16, tb, 0, stream>>>(ovf, ovfc, cnt, dinv, ovf_cap);

    init_y_h_k<<<(N * 32 + tb - 1) / tb, tb, 0, stream>>>(ue, ie, dinv, yA, N, U);

    const int wpb = tb / 64;
    int pgrid = (N + wpb - 1) / wpb;
    int qgrid = (2 * B + wpb - 1) / wpb;

    __half* yin = yA;
    __half* yout = yB;
    for (int layer = 0; layer < 4; ++layer) {
        // qgather of yin (layer's input = previous layer's fixed output)
        qgather_h_k<<<qgrid, tb, 0, stream>>>(yin, dinv, users, items, qacc, B, U,
                                              layer == 0 ? 1 : 0);
        prop_h_k<<<pgrid, tb, 0, stream>>>(cnt, colE, dinv, yin, yout, N);
        ovf_add_h_k<<<64, tb, 0, stream>>>(rovf, rovfc, dinv, yin, yout, ovf_cap);
        __half* tmp = yin; yin = yout; yout = tmp;
    }

    final_k<<<(B + wpb - 1) / wpb, tb, 0, stream>>>(qacc, yin, dinv, users, items,
                                                    (float*)d_out, B, U);
}

// Round 10
// 325.646 us; speedup vs baseline: 4.6710x; 1.0301x over previous
//
#include <hip/hip_runtime.h>
#include <hip/hip_fp16.h>

#define LAT 64
#define ELLC 64       // ELL row capacity (deg ~ Poisson(32); overflow handled)
#define RB 256        // rows per bucket
#define RBSH 8
#define MAXBUK 512    // static LDS sizing; nbuk = ceil(N/256) = 391 for N=100k

// ---------- phase 1: bin directed edges by row-bucket ----------
// Global atomics: one reservation per (block,bucket) ~= 200k total (vs 3.2M
// per-edge). 512 blocks x 1024 threads: ~2 blocks/CU, full latency hiding
// (R7's 256x256 ran at 9.5% occupancy / 0.5 TB/s).
// Packed word: (r & 255) << 17 | c   (needs N <= 131072).
__global__ void __launch_bounds__(1024)
bin_k(const int* __restrict__ eu, const int* __restrict__ ei,
      int* __restrict__ gcur, unsigned int* __restrict__ bbuf,
      int2* __restrict__ ovf, int* __restrict__ ovfc,
      int E, int U, int nbuk, int cap, int ovf_cap) {
    __shared__ int lcnt[MAXBUK];
    __shared__ int lbase[MAXBUK];
    int E2 = 2 * E;
    for (int i = threadIdx.x; i < nbuk; i += blockDim.x) lcnt[i] = 0;
    __syncthreads();
    int chunk = (E2 + gridDim.x - 1) / gridDim.x;
    int d0 = blockIdx.x * chunk;
    int d1 = min(E2, d0 + chunk);
    for (int d = d0 + threadIdx.x; d < d1; d += blockDim.x) {
        int r = (d < E) ? eu[d] : (ei[d - E] + U);
        atomicAdd(&lcnt[r >> RBSH], 1);
    }
    __syncthreads();
    for (int b = threadIdx.x; b < nbuk; b += blockDim.x)
        lbase[b] = atomicAdd(&gcur[b], lcnt[b]);      // global reservation
    __syncthreads();
    for (int d = d0 + threadIdx.x; d < d1; d += blockDim.x) {
        int r, c;
        if (d < E) { r = eu[d]; c = ei[d] + U; }
        else       { r = ei[d - E] + U; c = eu[d - E]; }
        int b = r >> RBSH;
        int pos = atomicAdd(&lbase[b], 1);            // LDS atomic (fast)
        if (pos < cap)
            bbuf[(size_t)b * cap + pos] = ((unsigned)(r & (RB - 1)) << 17) | (unsigned)c;
        else { int o = atomicAdd(ovfc, 1); if (o < ovf_cap) ovf[o] = make_int2(r, c); }
    }
}

// ---------- phase 2: per-bucket ELL build + dinv, LDS counters ----------
__global__ void __launch_bounds__(1024)
build_k(const unsigned int* __restrict__ bbuf, const int* __restrict__ gcur,
        int* __restrict__ cnt, int* __restrict__ colE, float* __restrict__ dinv,
        int2* __restrict__ rovf, int* __restrict__ rovfc,
        int N, int cap, int rovf_cap) {
    __shared__ int lcnt[RB];
    int b = blockIdx.x;
    for (int i = threadIdx.x; i < RB; i += blockDim.x) lcnt[i] = 0;
    __syncthreads();
    int nb = min(gcur[b], cap);
    const unsigned int* src = bbuf + (size_t)b * cap;
    for (int e = threadIdx.x; e < nb; e += blockDim.x) {
        unsigned w = src[e];
        int r7 = (int)(w >> 17);
        int c = (int)(w & 0x1FFFF);
        int pos = atomicAdd(&lcnt[r7], 1);
        int r = (b << RBSH) + r7;
        if (pos < ELLC) colE[(size_t)r * ELLC + pos] = c;   // 64KB L2 window
        else { int o = atomicAdd(rovfc, 1); if (o < rovf_cap) rovf[o] = make_int2(r, c); }
    }
    __syncthreads();
    for (int i = threadIdx.x; i < RB; i += blockDim.x) {
        int r = (b << RBSH) + i;
        if (r < N) {
            int d = lcnt[i];
            cnt[r] = d;
            dinv[r] = (d > 0) ? rsqrtf((float)d) : 0.0f;  // spill rows fixed in fix_k
        }
    }
}

// bin-phase spill fix-up + dinv recompute for touched rows (expected 0
// entries). SINGLE block: __syncthreads separates the adds from the dinv
// recompute so every touched row sees its FINAL cnt.
__global__ void __launch_bounds__(1024)
fix_k(const int2* __restrict__ ovf, const int* __restrict__ ovfc,
      int* __restrict__ cnt, int* __restrict__ colE, float* __restrict__ dinv,
      int2* __restrict__ rovf, int* __restrict__ rovfc,
      int ovf_cap, int rovf_cap) {
    int n = min(*ovfc, ovf_cap);
    for (int i = threadIdx.x; i < n; i += blockDim.x) {
        int r = ovf[i].x, c = ovf[i].y;
        int pos = atomicAdd(&cnt[r], 1);
        if (pos < ELLC) colE[(size_t)r * ELLC + pos] = c;
        else { int o = atomicAdd(rovfc, 1); if (o < rovf_cap) rovf[o] = make_int2(r, c); }
    }
    __syncthreads();
    for (int i = threadIdx.x; i < n; i += blockDim.x) {
        int r = ovf[i].x;
        int d = cnt[r];
        dinv[r] = (d > 0) ? rsqrtf((float)d) : 0.0f;
    }
}

// ---------- embedding init ----------

__global__ void init_y_h_k(const float* __restrict__ ue, const float* __restrict__ ie,
                           const float* __restrict__ dinv, __half* __restrict__ y,
                           int N, int U) {
    int i = blockIdx.x * blockDim.x + threadIdx.x;
    if (i >= N * 32) return;
    int idx = i * 2;
    int node = idx >> 6;
    const float* src = (node < U) ? (ue + idx) : (ie + (idx - U * LAT));
    float di = dinv[node];
    ((__half2*)y)[i] = __floats2half2_rn(di * src[0], di * src[1]);
}

// ---------- propagation + fused per-layer query gather ----------
// Waves [0,N): one wave per node; 8 groups x 8 lanes x 16B gathers (R6-proven;
// L2-line-rate-bound at ~47us: 6.4M random 64B lines/dispatch).
// Waves [N, N+2B): query gather qacc (+)= x = yin/dinv (yin final in stream
// order; first=1 initializes poisoned qacc on layer 0).
__global__ void __launch_bounds__(256)
prop_h_k(const int* __restrict__ cnt, const int* __restrict__ colE,
         const float* __restrict__ dinv, const __half* __restrict__ yin,
         __half* __restrict__ yout,
         const int* __restrict__ users, const int* __restrict__ items,
         float* __restrict__ qacc, int B, int first, int N) {
    int wave = blockIdx.x * (blockDim.x >> 6) + (threadIdx.x >> 6);
    int lane = threadIdx.x & 63;
    if (wave >= N) {
        int qw = wave - N;
        if (qw >= 2 * B) return;
        int node = (qw < B) ? users[qw] : (items[qw - B] + 0);
        if (qw >= B) node = items[qw - B] + (N - (N - 0)) ;  // placeholder avoided below
        return;  // unreachable real path — replaced by qnode computation below
    }
    int g = lane >> 3;        // group 0..7: neighbor j = 8*it + g
    int t = lane & 7;         // 16B chunk: dims 8t..8t+7
    int len = min(cnt[wave], ELLC);
    const int* cp = colE + (size_t)wave * ELLC;
    int lm0 = max(len - 1, 0);
    int call = cp[min(lane, lm0)];        // one coalesced 256B col load
    const uint4* y16 = (const uint4*)yin;

    float2 acc[4];
#pragma unroll
    for (int d = 0; d < 4; ++d) acc[d] = make_float2(0.f, 0.f);

    int nb = (len + 7) >> 3;              // wave-uniform trip count (0..8)
    int it = 0;
    for (; it + 4 <= nb; it += 4) {
        int j0 = (it << 3) + g;
        int c0 = __shfl(call, j0);
        int c1 = __shfl(call, j0 + 8);
        int c2 = __shfl(call, j0 + 16);
        int c3 = __shfl(call, j0 + 24);
        uint4 v0 = y16[(size_t)c0 * 8 + t];
        uint4 v1 = y16[(size_t)c1 * 8 + t];
        uint4 v2 = y16[(size_t)c2 * 8 + t];
        uint4 v3 = y16[(size_t)c3 * 8 + t];
        if (j0 < len) {
            const __half2* h = (const __half2*)&v0;
#pragma unroll
            for (int d = 0; d < 4; ++d) { float2 f = __half22float2(h[d]); acc[d].x += f.x; acc[d].y += f.y; }
        }
        if (j0 + 8 < len) {
            const __half2* h = (const __half2*)&v1;
#pragma unroll
            for (int d = 0; d < 4; ++d) { float2 f = __half22float2(h[d]); acc[d].x += f.x; acc[d].y += f.y; }
        }
        if (j0 + 16 < len) {
            const __half2* h = (const __half2*)&v2;
#pragma unroll
            for (int d = 0; d < 4; ++d) { float2 f = __half22float2(h[d]); acc[d].x += f.x; acc[d].y += f.y; }
        }
        if (j0 + 24 < len) {
            const __half2* h = (const __half2*)&v3;
#pragma unroll
            for (int d = 0; d < 4; ++d) { float2 f = __half22float2(h[d]); acc[d].x += f.x; acc[d].y += f.y; }
        }
    }
    for (; it < nb; ++it) {
        int j0 = (it << 3) + g;
        int c0 = __shfl(call, j0);
        uint4 v0 = y16[(size_t)c0 * 8 + t];
        if (j0 < len) {
            const __half2* h = (const __half2*)&v0;
#pragma unroll
            for (int d = 0; d < 4; ++d) { float2 f = __half22float2(h[d]); acc[d].x += f.x; acc[d].y += f.y; }
        }
    }
#pragma unroll
    for (int d = 0; d < 4; ++d) {
        acc[d].x += __shfl_xor(acc[d].x, 8);  acc[d].y += __shfl_xor(acc[d].y, 8);
        acc[d].x += __shfl_xor(acc[d].x, 16); acc[d].y += __shfl_xor(acc[d].y, 16);
        acc[d].x += __shfl_xor(acc[d].x, 32); acc[d].y += __shfl_xor(acc[d].y, 32);
    }
    if (g == 0) {
        float di = dinv[wave];
        float f = di * di;
        __half2 o[4];
#pragma unroll
        for (int d = 0; d < 4; ++d)
            o[d] = __floats2half2_rn(f * acc[d].x, f * acc[d].y);
        ((uint4*)yout)[(size_t)wave * 8 + t] = *(const uint4*)o;
    }
}

// fused query path done right: separate kernel body via a U parameter would
// have been needed in prop; simpler and equally cheap — dedicated kernel is
// replaced by extra waves in prop2_h_k below. To keep prop_h_k clean (above
// stub returns immediately and is never launched with waves >= N), we use
// this wrapper that prop launches route through:
__global__ void __launch_bounds__(256)
prop2_h_k(const int* __restrict__ cnt, const int* __restrict__ colE,
          const float* __restrict__ dinv, const __half* __restrict__ yin,
          __half* __restrict__ yout,
          const int* __restrict__ users, const int* __restrict__ items,
          float* __restrict__ qacc, int B, int U, int first, int N) {
    int wave = blockIdx.x * (blockDim.x >> 6) + (threadIdx.x >> 6);
    int lane = threadIdx.x & 63;
    if (wave >= N) {
        int qw = wave - N;
        if (qw >= 2 * B) return;
        int node = (qw < B) ? users[qw] : (items[qw - B] + U);
        float di = dinv[node];
        float r = (di > 0.0f) ? (1.0f / di) : 0.0f;
        float v = __half2float(yin[(size_t)node * LAT + lane]) * r;
        if (first) qacc[qw * LAT + lane] = v;
        else       qacc[qw * LAT + lane] += v;
        return;
    }
    int g = lane >> 3;
    int t = lane & 7;
    int len = min(cnt[wave], ELLC);
    const int* cp = colE + (size_t)wave * ELLC;
    int lm0 = max(len - 1, 0);
    int call = cp[min(lane, lm0)];
    const uint4* y16 = (const uint4*)yin;

    float2 acc[4];
#pragma unroll
    for (int d = 0; d < 4; ++d) acc[d] = make_float2(0.f, 0.f);

    int nb = (len + 7) >> 3;
    int it = 0;
    for (; it + 4 <= nb; it += 4) {
        int j0 = (it << 3) + g;
        int c0 = __shfl(call, j0);
        int c1 = __shfl(call, j0 + 8);
        int c2 = __shfl(call, j0 + 16);
        int c3 = __shfl(call, j0 + 24);
        uint4 v0 = y16[(size_t)c0 * 8 + t];
        uint4 v1 = y16[(size_t)c1 * 8 + t];
        uint4 v2 = y16[(size_t)c2 * 8 + t];
        uint4 v3 = y16[(size_t)c3 * 8 + t];
        if (j0 < len) {
            const __half2* h = (const __half2*)&v0;
#pragma unroll
            for (int d = 0; d < 4; ++d) { float2 f = __half22float2(h[d]); acc[d].x += f.x; acc[d].y += f.y; }
        }
        if (j0 + 8 < len) {
            const __half2* h = (const __half2*)&v1;
#pragma unroll
            for (int d = 0; d < 4; ++d) { float2 f = __half22float2(h[d]); acc[d].x += f.x; acc[d].y += f.y; }
        }
        if (j0 + 16 < len) {
            const __half2* h = (const __half2*)&v2;
#pragma unroll
            for (int d = 0; d < 4; ++d) { float2 f = __half22float2(h[d]); acc[d].x += f.x; acc[d].y += f.y; }
        }
        if (j0 + 24 < len) {
            const __half2* h = (const __half2*)&v3;
#pragma unroll
            for (int d = 0; d < 4; ++d) { float2 f = __half22float2(h[d]); acc[d].x += f.x; acc[d].y += f.y; }
        }
    }
    for (; it < nb; ++it) {
        int j0 = (it << 3) + g;
        int c0 = __shfl(call, j0);
        uint4 v0 = y16[(size_t)c0 * 8 + t];
        if (j0 < len) {
            const __half2* h = (const __half2*)&v0;
#pragma unroll
            for (int d = 0; d < 4; ++d) { float2 f = __half22float2(h[d]); acc[d].x += f.x; acc[d].y += f.y; }
        }
    }
#pragma unroll
    for (int d = 0; d < 4; ++d) {
        acc[d].x += __shfl_xor(acc[d].x, 8);  acc[d].y += __shfl_xor(acc[d].y, 8);
        acc[d].x += __shfl_xor(acc[d].x, 16); acc[d].y += __shfl_xor(acc[d].y, 16);
        acc[d].x += __shfl_xor(acc[d].x, 32); acc[d].y += __shfl_xor(acc[d].y, 32);
    }
    if (g == 0) {
        float di = dinv[wave];
        float f = di * di;
        __half2 o[4];
#pragma unroll
        for (int d = 0; d < 4; ++d)
            o[d] = __floats2half2_rn(f * acc[d].x, f * acc[d].y);
        ((uint4*)yout)[(size_t)wave * 8 + t] = *(const uint4*)o;
    }
}

// rare ELL row-overflow fix-up (exact via CAS on packed half2)
__global__ void ovf_add_h_k(const int2* __restrict__ rovf, const int* __restrict__ rovfc,
                            const float* __restrict__ dinv, const __half* __restrict__ yin,
                            __half* __restrict__ yout, int cap) {
    int n = min(*rovfc, cap);
    int wave = blockIdx.x * (blockDim.x >> 6) + (threadIdx.x >> 6);
    int lane = threadIdx.x & 63;
    int nwv = gridDim.x * (blockDim.x >> 6);
    for (int o = wave; o < n; o += nwv) {
        int r = rovf[o].x, c = rovf[o].y;
        if (lane < 32) {
            float f = dinv[r] * dinv[r];
            __half2 v = ((const __half2*)(yin + (size_t)c * LAT))[lane];
            float ax = f * __low2float(v), ay = f * __high2float(v);
            unsigned int* addr = (unsigned int*)(yout + (size_t)r * LAT) + lane;
            unsigned int old = *addr;
            while (true) {
                __half2 oh = *(__half2*)&old;
                __half2 nh = __floats2half2_rn(__low2float(oh) + ax, __high2float(oh) + ay);
                unsigned int nu = *(unsigned int*)&nh;
                unsigned int prev = atomicCAS(addr, old, nu);
                if (prev == old) break;
                old = prev;
            }
        }
    }
}

// final: qacc += x4 at queried nodes, then gamma = dot/25 (fused last qgather)
__global__ void final_k(const float* __restrict__ qacc, const __half* __restrict__ y4,
                        const float* __restrict__ dinv,
                        const int* __restrict__ users, const int* __restrict__ items,
                        float* __restrict__ out, int B, int U) {
    int wave = blockIdx.x * (blockDim.x >> 6) + (threadIdx.x >> 6);
    int lane = threadIdx.x & 63;
    if (wave >= B) return;
    int un = users[wave];
    int in = items[wave] + U;
    float du = dinv[un], di = dinv[in];
    float ru = (du > 0.f) ? (1.f / du) : 0.f;
    float ri = (di > 0.f) ? (1.f / di) : 0.f;
    float au = qacc[wave * LAT + lane] + __half2float(y4[(size_t)un * LAT + lane]) * ru;
    float ai = qacc[(wave + B) * LAT + lane] + __half2float(y4[(size_t)in * LAT + lane]) * ri;
    float p = au * ai;
#pragma unroll
    for (int off = 32; off > 0; off >>= 1) p += __shfl_down(p, off);
    if (lane == 0) out[wave] = p * (1.0f / 25.0f);
}

extern "C" void kernel_launch(void* const* d_in, const int* in_sizes, int n_in,
                              void* d_out, int out_size, void* d_ws, size_t ws_size,
                              hipStream_t stream) {
    const float* ue = (const float*)d_in[0];
    const float* ie = (const float*)d_in[1];
    const int* edge = (const int*)d_in[2];
    const int* users = (const int*)d_in[3];
    const int* items = (const int*)d_in[4];

    const int U = in_sizes[0] / LAT;
    const int I = in_sizes[1] / LAT;
    const int N = U + I;
    const int E = in_sizes[2] / 2;
    const int B = in_sizes[3];
    const int* eu = edge;
    const int* ei = edge + E;

    const int nbuk = (N + RB - 1) / RB;                    // 391 for N=100k
    const int cap = ((2 * E / nbuk) * 5 / 4 + 255) & ~255; // ~25% slack

    char* ws = (char*)d_ws;
    size_t off = 0;
    auto alloc = [&](size_t bytes) -> void* {
        void* p = ws + off;
        off += (bytes + 255) & ~(size_t)255;
        return p;
    };
    int*      cnt  = (int*)alloc((size_t)4 * N);
    float*    dinv = (float*)alloc((size_t)4 * N);
    int*      colE = (int*)alloc((size_t)4 * N * ELLC);     // 25.6 MB
    __half*   yA   = (__half*)alloc((size_t)2 * N * LAT);   // 12.8 MB
    __half*   yB   = (__half*)alloc((size_t)2 * N * LAT);
    float*    qacc = (float*)alloc((size_t)4 * 2 * B * LAT);
    unsigned* bbuf = (unsigned*)alloc((size_t)4 * nbuk * cap);  // ~16 MB
    // gcur and ovfc adjacent -> single memset covers both
    size_t zoff = off;
    int*      gcur = (int*)alloc((size_t)4 * nbuk);
    int*      ovfc = (int*)alloc(256);   // [0]=bin spill, [64]=row ovf
    size_t zbytes = off - zoff;
    size_t remain = (ws_size > off + 256) ? (ws_size - off - 256) : 0;
    int ovf_cap = (int)min((size_t)131072, remain / (2 * sizeof(int2)));
    int2* ovf  = (int2*)alloc((size_t)ovf_cap * sizeof(int2));
    int2* rovf = (int2*)alloc((size_t)ovf_cap * sizeof(int2));
    int* rovfc = ovfc + 64;

    hipError_t _e = hipMemsetAsync(gcur, 0, zbytes, stream); (void)_e;

    const int tb = 256;

    bin_k<<<512, 1024, 0, stream>>>(eu, ei, gcur, bbuf, ovf, ovfc, E, U, nbuk, cap, ovf_cap);
    build_k<<<nbuk, 1024, 0, stream>>>(bbuf, gcur, cnt, colE, dinv, rovf, rovfc, N, cap, ovf_cap);
    fix_k<<<1, 1024, 0, stream>>>(ovf, ovfc, cnt, colE, dinv, rovf, rovfc, ovf_cap, ovf_cap);

    init_y_h_k<<<(N * 32 + tb - 1) / tb, tb, 0, stream>>>(ue, ie, dinv, yA, N, U);

    const int wpb = tb / 64;
    int pgrid = (N + 2 * B + wpb - 1) / wpb;   // row waves + fused query waves

    __half* yin = yA;
    __half* yout = yB;
    for (int layer = 0; layer < 4; ++layer) {
        prop2_h_k<<<pgrid, tb, 0, stream>>>(cnt, colE, dinv, yin, yout,
                                            users, items, qacc, B, U,
                                            layer == 0 ? 1 : 0, N);
        ovf_add_h_k<<<64, tb, 0, stream>>>(rovf, rovfc, dinv, yin, yout, ovf_cap);
        __half* tmp = yin; yin = yout; yout = tmp;
    }

    final_k<<<(B + wpb - 1) / wpb, tb, 0, stream>>>(qacc, yin, dinv, users, items,
                                                    (float*)d_out, B, U);
}